// Round 15
// baseline (624.223 us; speedup 1.0000x reference)
//
#include <hip/hip_runtime.h>
#include <hip/hip_bf16.h>

typedef __attribute__((ext_vector_type(8))) short bf16x8;
typedef __attribute__((ext_vector_type(4))) float f32x4;
typedef __attribute__((ext_vector_type(16))) float f32x16;
typedef __attribute__((ext_vector_type(2))) unsigned uint2x;

#define AS1(p) ((const __attribute__((address_space(1))) void*)(p))
#define AS3(p) ((__attribute__((address_space(3))) void*)(p))

__device__ inline unsigned cvtpk_bf16(float lo, float hi) {
  unsigned r;
  asm("v_cvt_pk_bf16_f32 %0, %1, %2" : "=v"(r) : "v"(lo), "v"(hi));
  return r;
}

__device__ inline uint2x plswap(unsigned a, unsigned b) {
  return __builtin_amdgcn_permlane32_swap(a, b, false, false);
}

// ---------------- fused prep: 4 weight transposes + Q conversion (one launch) -------
__global__ __launch_bounds__(256) void prep(const float* __restrict__ Wq,
                                            const float* __restrict__ Wo,
                                            const float* __restrict__ Wk,
                                            const float* __restrict__ Wv,
                                            const float* __restrict__ q_in,
                                            __hip_bfloat16* __restrict__ WqT,
                                            __hip_bfloat16* __restrict__ WoT,
                                            __hip_bfloat16* __restrict__ WkT,
                                            __hip_bfloat16* __restrict__ WvT,
                                            __hip_bfloat16* __restrict__ qc) {
  const int z = blockIdx.z;
  if (z == 4) {
    const size_t b0 = (size_t)blockIdx.x * 4096;
#pragma unroll
    for (int c = 0; c < 4; ++c) {
      const size_t i = b0 + c * 1024 + threadIdx.x * 4;
      float4 v = *(const float4*)(q_in + i);
      union { __hip_bfloat16 h[4]; ushort4 u; } o;
      o.h[0] = __float2bfloat16(v.x);
      o.h[1] = __float2bfloat16(v.y);
      o.h[2] = __float2bfloat16(v.z);
      o.h[3] = __float2bfloat16(v.w);
      *(ushort4*)(qc + i) = o.u;
    }
    return;
  }
  const int N = (z < 2) ? 4096 : 1024;
  const int n0 = (blockIdx.x & 63) << 6;
  if (n0 >= N) return;
  const int k0 = (blockIdx.x >> 6) << 6;
  const float* W = (z == 0) ? Wq : (z == 1) ? Wo : (z == 2) ? Wk : Wv;
  __hip_bfloat16* WT = (z == 0) ? WqT : (z == 1) ? WoT : (z == 2) ? WkT : WvT;
  __shared__ float t[64][68];
  const int tx = threadIdx.x & 15, ty = threadIdx.x >> 4;
#pragma unroll
  for (int j = 0; j < 4; ++j) {
    const int k = ty + j * 16;
    float4 v = *(const float4*)(W + (size_t)(k0 + k) * N + n0 + tx * 4);
    t[tx * 4 + 0][k] = v.x;
    t[tx * 4 + 1][k] = v.y;
    t[tx * 4 + 2][k] = v.z;
    t[tx * 4 + 3][k] = v.w;
  }
  __syncthreads();
#pragma unroll
  for (int j = 0; j < 4; ++j) {
    const int n = ty + j * 16;
    float4 v = *(const float4*)(&t[n][tx * 4]);
    union { __hip_bfloat16 h[4]; ushort4 u; } o;
    o.h[0] = __float2bfloat16(v.x);
    o.h[1] = __float2bfloat16(v.y);
    o.h[2] = __float2bfloat16(v.z);
    o.h[3] = __float2bfloat16(v.w);
    *(ushort4*)(WT + (size_t)(n0 + n) * 4096 + k0 + tx * 4) = o.u;
  }
}

// K+V conversions (after gemm256-Q frees xbuf/WqT)
__global__ __launch_bounds__(256) void xconv_kv(const float* __restrict__ k_in,
                                                const float* __restrict__ v_in,
                                                __hip_bfloat16* __restrict__ kc,
                                                __hip_bfloat16* __restrict__ vc) {
  const float* in = blockIdx.y ? v_in : k_in;
  __hip_bfloat16* out = blockIdx.y ? vc : kc;
  size_t i = ((size_t)blockIdx.x * 256 + threadIdx.x) * 4;
  float4 v = *(const float4*)(in + i);
  union { __hip_bfloat16 h[4]; ushort4 u; } o;
  o.h[0] = __float2bfloat16(v.x);
  o.h[1] = __float2bfloat16(v.y);
  o.h[2] = __float2bfloat16(v.z);
  o.h[3] = __float2bfloat16(v.w);
  *(ushort4*)(out + i) = o.u;
}

// ---------------- shared 8-phase GEMM machinery (T2+T3+T4+T5) ----------------

__device__ inline int tile_off(int row, int k) {
  return (((row >> 4) << 1) + (k >> 5)) * 512 + (row & 15) * 32 +
         ((k & 31) ^ ((row & 8) << 1));
}

__device__ inline void stageA(const __hip_bfloat16* __restrict__ src, int ld, int row0,
                              int kt, int h, __hip_bfloat16* ldsT, int w, int lane) {
#pragma unroll
  for (int li = 0; li < 2; ++li) {
    const int t = li * 8 + w;
    const int grp = ((t >> 3) << 1) + h;
    const int srl = (t & 7) >> 1, sk = t & 1;
    const int rowbase = grp * 64 + srl * 16;
    __hip_bfloat16* dst = ldsT + ((((rowbase >> 4) << 1) + sk) << 9);
    const int r = lane >> 2;
    const int ku = (lane & 3) ^ ((r & 8) >> 2);
    __builtin_amdgcn_global_load_lds(
        AS1(src + (size_t)(row0 + rowbase + r) * ld + kt + (sk << 5) + (ku << 3)),
        AS3(dst), 16, 0, 0);
  }
}

__device__ inline void stageB(const __hip_bfloat16* __restrict__ src, int ld, int col0,
                              int kt, int h, __hip_bfloat16* ldsT, int w, int lane) {
#pragma unroll
  for (int li = 0; li < 2; ++li) {
    const int t = li * 8 + w;
    const int q = t >> 2;
    const int srl = (t >> 1) & 1, sk = t & 1;
    const int colbase = q * 64 + h * 32 + srl * 16;
    __hip_bfloat16* dst = ldsT + ((((colbase >> 4) << 1) + sk) << 9);
    const int r = lane >> 2;
    const int ku = (lane & 3) ^ ((r & 8) >> 2);
    __builtin_amdgcn_global_load_lds(
        AS1(src + (size_t)(col0 + colbase + r) * ld + kt + (sk << 5) + (ku << 3)),
        AS3(dst), 16, 0, 0);
  }
}

template <int OUT_F32>
__global__ __launch_bounds__(512, 1) void gemm256(const __hip_bfloat16* __restrict__ A,
                                                  const __hip_bfloat16* __restrict__ BT,
                                                  void* __restrict__ Cout,
                                                  int M, int N, int K) {
  __shared__ __align__(16) __hip_bfloat16 lds[2][2][16384];
  const int tid = threadIdx.x;
  const int lane = tid & 63, w = tid >> 6;
  const int l15 = lane & 15, lg = lane >> 4;
  const int wm = w >> 2, wn = w & 3;
  const int nbx = N >> 8;
  const int nwg = (M >> 8) * nbx;
  const int bid = blockIdx.x;
  const int swz = (bid & 7) * (nwg >> 3) + (bid >> 3);
  const int m0 = (swz / nbx) << 8, n0 = (swz % nbx) << 8;

  f32x4 acc[8][4] = {};
  const int NT = K >> 6;

  stageA(A, K, m0, 0, 0, &lds[0][0][0], w, lane);
  stageB(BT, K, n0, 0, 0, &lds[0][1][0], w, lane);
  stageA(A, K, m0, 0, 1, &lds[0][0][0], w, lane);
  stageB(BT, K, n0, 0, 1, &lds[0][1][0], w, lane);
  stageA(A, K, m0, 64, 0, &lds[1][0][0], w, lane);
  stageB(BT, K, n0, 64, 0, &lds[1][1][0], w, lane);
  asm volatile("s_waitcnt vmcnt(4)" ::: "memory");
  __builtin_amdgcn_s_barrier();

  for (int j = 0; j < NT; ++j) {
    const int buf = j & 1;
    const __hip_bfloat16* Ab = &lds[buf][0][0];
    const __hip_bfloat16* Bb = &lds[buf][1][0];
    __hip_bfloat16* An = &lds[buf ^ 1][0][0];
    __hip_bfloat16* Bn = &lds[buf ^ 1][1][0];
    __hip_bfloat16* Ac = &lds[buf][0][0];
    __hip_bfloat16* Bc = &lds[buf][1][0];
    const int kt1 = (j + 1) << 6, kt2 = (j + 2) << 6;
    const bool s1 = (j + 1) < NT, s2 = (j + 2) < NT;

    auto phase = [&](int rq, int cq, int sid) {
      bf16x8 af[2][4], bfr[2][2];
#pragma unroll
      for (int kk = 0; kk < 2; ++kk) {
#pragma unroll
        for (int rf = 0; rf < 4; ++rf)
          af[kk][rf] = *(const bf16x8*)(Ab +
              tile_off(wm * 128 + (rq * 4 + rf) * 16 + l15, kk * 32 + lg * 8));
#pragma unroll
        for (int cf = 0; cf < 2; ++cf)
          bfr[kk][cf] = *(const bf16x8*)(Bb +
              tile_off(wn * 64 + (cq * 2 + cf) * 16 + l15, kk * 32 + lg * 8));
      }
      if (sid == 0)      { if (s1) stageA(A, K, m0, kt1, 1, An, w, lane); }
      else if (sid == 1) { if (s1) stageB(BT, K, n0, kt1, 1, Bn, w, lane); }
      else if (sid == 2) { if (s2) stageA(A, K, m0, kt2, 0, Ac, w, lane); }
      else {
        if (s2) stageB(BT, K, n0, kt2, 0, Bc, w, lane);
        if (s2) asm volatile("s_waitcnt vmcnt(4)" ::: "memory");
        else    asm volatile("s_waitcnt vmcnt(0)" ::: "memory");
      }
      __builtin_amdgcn_s_barrier();
      asm volatile("s_waitcnt lgkmcnt(0)" ::: "memory");
      __builtin_amdgcn_sched_barrier(0);
      __builtin_amdgcn_s_setprio(1);
#pragma unroll
      for (int kk = 0; kk < 2; ++kk)
#pragma unroll
        for (int rf = 0; rf < 4; ++rf)
#pragma unroll
          for (int cf = 0; cf < 2; ++cf)
            acc[rq * 4 + rf][cq * 2 + cf] = __builtin_amdgcn_mfma_f32_16x16x32_bf16(
                af[kk][rf], bfr[kk][cf], acc[rq * 4 + rf][cq * 2 + cf], 0, 0, 0);
      __builtin_amdgcn_s_setprio(0);
      __builtin_amdgcn_s_barrier();
    };
    phase(0, 0, 0);
    phase(0, 1, 1);
    phase(1, 0, 2);
    phase(1, 1, 3);
  }

#pragma unroll
  for (int rf = 0; rf < 8; ++rf)
#pragma unroll
    for (int cf = 0; cf < 4; ++cf)
#pragma unroll
      for (int i = 0; i < 4; ++i) {
        const size_t row = (size_t)(m0 + wm * 128 + rf * 16 + lg * 4 + i);
        const size_t col = (size_t)(n0 + wn * 64 + cf * 16 + l15);
        if (OUT_F32)
          ((float*)Cout)[row * N + col] = acc[rf][cf][i];
        else
          ((__hip_bfloat16*)Cout)[row * N + col] = __float2bfloat16(acc[rf][cf][i]);
      }
}

// ---------------- 8-phase K/V projection + fused RoPE-K epilogue --------------------
__global__ __launch_bounds__(512, 1) void gemm_kv8(const __hip_bfloat16* __restrict__ Ak,
                                                   const __hip_bfloat16* __restrict__ Av,
                                                   const __hip_bfloat16* __restrict__ BkT,
                                                   const __hip_bfloat16* __restrict__ BvT,
                                                   const int* __restrict__ pos,
                                                   __hip_bfloat16* __restrict__ Kp,
                                                   __hip_bfloat16* __restrict__ VT) {
  __shared__ __align__(16) __hip_bfloat16 lds[2][24576];
  const int zz = blockIdx.z;
  const __hip_bfloat16* A  = zz ? Av : Ak;
  const __hip_bfloat16* BT = zz ? BvT : BkT;
  const int K = 4096;
  const int tid = threadIdx.x;
  const int lane = tid & 63, w = tid >> 6;
  const int l15 = lane & 15, lg = lane >> 4;
  const int wm = w >> 2, wn = w & 3;
  const int bid = blockIdx.x;
  const int swz = (bid & 7) * 16 + (bid >> 3);
  const int m0 = (swz >> 2) << 7;
  const int n0 = (swz & 3) << 8;

  auto stgA = [&](int kt, int h, __hip_bfloat16* ldsA) {
    const int r16 = 2 * h + ((w >> 2) << 2) + ((w >> 1) & 1);
    const int sk = w & 1;
    __hip_bfloat16* dst = ldsA + (((r16 << 1) + sk) << 9);
    const int r = lane >> 2;
    const int ku = (lane & 3) ^ ((r & 8) >> 2);
    __builtin_amdgcn_global_load_lds(
        AS1(A + (size_t)(m0 + r16 * 16 + r) * K + kt + (sk << 5) + (ku << 3)),
        AS3(dst), 16, 0, 0);
  };
  auto stgB = [&](int kt, int h, __hip_bfloat16* ldsB) {
#pragma unroll
    for (int li = 0; li < 2; ++li) {
      const int idx = li * 8 + w;
      const int r16 = ((idx >> 2) << 2) + 2 * h + ((idx >> 1) & 1);
      const int sk = idx & 1;
      __hip_bfloat16* dst = ldsB + (((r16 << 1) + sk) << 9);
      const int r = lane >> 2;
      const int ku = (lane & 3) ^ ((r & 8) >> 2);
      __builtin_amdgcn_global_load_lds(
          AS1(BT + (size_t)(n0 + r16 * 16 + r) * K + kt + (sk << 5) + (ku << 3)),
          AS3(dst), 16, 0, 0);
    }
  };

  f32x4 acc[4][4] = {};
  const int NT = K >> 6;

  stgA(0, 0, &lds[0][0]);
  stgB(0, 0, &lds[0][8192]);
  stgA(0, 1, &lds[0][0]);
  stgB(0, 1, &lds[0][8192]);
  stgA(64, 0, &lds[1][0]);
  stgB(64, 0, &lds[1][8192]);
  asm volatile("s_waitcnt vmcnt(3)" ::: "memory");
  __builtin_amdgcn_s_barrier();

  for (int j = 0; j < NT; ++j) {
    const int buf = j & 1;
    const __hip_bfloat16* Ab = &lds[buf][0];
    const __hip_bfloat16* Bb = &lds[buf][8192];
    __hip_bfloat16* An = &lds[buf ^ 1][0];
    __hip_bfloat16* Bn = &lds[buf ^ 1][8192];
    __hip_bfloat16* Ac = &lds[buf][0];
    __hip_bfloat16* Bc = &lds[buf][8192];
    const int kt1 = (j + 1) << 6, kt2 = (j + 2) << 6;
    const bool s1 = (j + 1) < NT, s2 = (j + 2) < NT;

    auto phase = [&](int rq, int cq, int sid) {
      bf16x8 af[2][2], bfr[2][2];
#pragma unroll
      for (int kk = 0; kk < 2; ++kk) {
#pragma unroll
        for (int rf = 0; rf < 2; ++rf)
          af[kk][rf] = *(const bf16x8*)(Ab +
              tile_off(wm * 64 + (rq * 2 + rf) * 16 + l15, kk * 32 + lg * 8));
#pragma unroll
        for (int cf = 0; cf < 2; ++cf)
          bfr[kk][cf] = *(const bf16x8*)(Bb +
              tile_off(wn * 64 + (cq * 2 + cf) * 16 + l15, kk * 32 + lg * 8));
      }
      if (sid == 0)      { if (s1) stgA(kt1, 1, An); }
      else if (sid == 1) { if (s1) stgB(kt1, 1, Bn); }
      else if (sid == 2) { if (s2) stgA(kt2, 0, Ac); }
      else {
        if (s2) stgB(kt2, 0, Bc);
        if (s2) asm volatile("s_waitcnt vmcnt(3)" ::: "memory");
        else    asm volatile("s_waitcnt vmcnt(0)" ::: "memory");
      }
      __builtin_amdgcn_s_barrier();
      asm volatile("s_waitcnt lgkmcnt(0)" ::: "memory");
      __builtin_amdgcn_sched_barrier(0);
      __builtin_amdgcn_s_setprio(1);
#pragma unroll
      for (int kk = 0; kk < 2; ++kk)
#pragma unroll
        for (int rf = 0; rf < 2; ++rf)
#pragma unroll
          for (int cf = 0; cf < 2; ++cf)
            acc[rq * 2 + rf][cq * 2 + cf] = __builtin_amdgcn_mfma_f32_16x16x32_bf16(
                af[kk][rf], bfr[kk][cf], acc[rq * 2 + rf][cq * 2 + cf], 0, 0, 0);
      __builtin_amdgcn_s_setprio(0);
      __builtin_amdgcn_s_barrier();
    };
    phase(0, 0, 0);
    phase(0, 1, 1);
    phase(1, 0, 2);
    phase(1, 1, 3);
  }

  if (zz == 0) {
    __syncthreads();
    __hip_bfloat16* T = &lds[0][0];         // [128][264]
    const int TS = 264;
#pragma unroll
    for (int rf = 0; rf < 4; ++rf)
#pragma unroll
      for (int cf = 0; cf < 4; ++cf)
#pragma unroll
        for (int i = 0; i < 4; ++i)
          T[(wm * 64 + rf * 16 + lg * 4 + i) * TS + wn * 64 + cf * 16 + l15] =
              __float2bfloat16(acc[rf][cf][i]);
    __syncthreads();
    const int row = tid >> 2, quad = tid & 3;
    const int gr = m0 + row;
    const float p = (float)pos[gr];
#pragma unroll
    for (int qb = 0; qb < 4; ++qb) {
      const int bi = quad + qb * 4;
      const int hl = bi >> 3, jb = (bi & 7) * 8;
      bf16x8 lo  = *(const bf16x8*)&T[row * TS + hl * 128 + jb];
      bf16x8 hi8 = *(const bf16x8*)&T[row * TS + hl * 128 + jb + 64];
      union { __hip_bfloat16 h[8]; bf16x8 v; } o0, o1;
#pragma unroll
      for (int e = 0; e < 8; ++e) {
        const int j = jb + e;
        const float fr = p * exp2f((float)j * -0.2076205059304601f);
        float sn, cs;
        __sincosf(fr, &sn, &cs);
        const float x0 = __uint_as_float(((unsigned)(unsigned short)lo[e]) << 16);
        const float x1 = __uint_as_float(((unsigned)(unsigned short)hi8[e]) << 16);
        o0.h[e] = __float2bfloat16(x0 * cs - x1 * sn);
        o1.h[e] = __float2bfloat16(x1 * cs + x0 * sn);
      }
      *(bf16x8*)(Kp + (size_t)gr * 1024 + n0 + hl * 128 + jb)      = o0.v;
      *(bf16x8*)(Kp + (size_t)gr * 1024 + n0 + hl * 128 + jb + 64) = o1.v;
    }
  } else {
    const int b = m0 >> 11, s0g = m0 & 2047;
#pragma unroll
    for (int rf = 0; rf < 4; ++rf)
#pragma unroll
      for (int cf = 0; cf < 4; ++cf) {
        const int d = n0 + wn * 64 + cf * 16 + l15;
        const int g = d >> 7, dl = d & 127;
        const int srow = s0g + wm * 64 + rf * 16 + lg * 4;
        union { __hip_bfloat16 h[4]; unsigned long long u; } pkv;
#pragma unroll
        for (int i = 0; i < 4; ++i) pkv.h[i] = __float2bfloat16(acc[rf][cf][i]);
        *(unsigned long long*)(VT + ((size_t)(b * 8 + g) * 128 + dl) * 2048 + srow) = pkv.u;
      }
  }
}

// ---------------- flash attention (8-warp 32x32; counted-vmcnt pipeline, T4) ---------
// K staged 3-deep (Ks[3], issued for tile j+2), V 2-deep (Vs[2], for j+1), issue order
// V-then-K. In-order vmcnt: waiting vmcnt(6) leaves {K(j+1),V(j+1),K(j+2)} in flight
// while guaranteeing K(j),V(j) landed -> no full drain at barriers (m97-stall removed).
// Two raw s_barriers/iter: top (RAW, after counted vmcnt), bottom (WAR before stages).
// LDS 80 KB -> 2 blocks/CU. Max-free softmax + MFMA lsum as before.
__global__ __launch_bounds__(512) void attn(const __hip_bfloat16* __restrict__ Q,
                                            const __hip_bfloat16* __restrict__ Kp,
                                            const __hip_bfloat16* __restrict__ VT,
                                            const int* __restrict__ pos,
                                            __hip_bfloat16* __restrict__ ctx,
                                            float qs) {
  const int tid = threadIdx.x;
  const int lane = tid & 63, w = tid >> 6;
  const int l31 = lane & 31, hi = lane >> 5;
  const int qt = blockIdx.x, h = blockIdx.y, b = blockIdx.z;
  const int kvh = h >> 2;
  const int q0 = qt * 256 + w * 32;

  const __hip_bfloat16* Qh = Q + (size_t)(b * 2048) * 4096 + h * 128;
  const __hip_bfloat16* Kh = Kp + (size_t)(b * 2048) * 1024 + kvh * 128;
  const __hip_bfloat16* Vh = VT + (size_t)(b * 8 + kvh) * 128 * 2048;

  __shared__ __hip_bfloat16 Ks[3][64 * 128];   // 48 KB, 3-deep
  __shared__ __hip_bfloat16 Vs[2][128 * 64];   // 32 KB, 2-deep

  auto stageK = [&](int buf, int s0) {
#pragma unroll
    for (int jj = 0; jj < 2; ++jj) {
      const int idx = w * 64 + lane + jj * 512;
      const int rK = idx >> 4, uK = idx & 15;
      __builtin_amdgcn_global_load_lds(
          AS1(Kh + (size_t)(s0 + rK) * 1024 + ((uK ^ (rK & 7)) << 3)),
          AS3(&Ks[buf][(w * 64 + jj * 512) * 8]), 16, 0, 0);
    }
  };
  auto stageV = [&](int buf, int s0) {
#pragma unroll
    for (int jj = 0; jj < 2; ++jj) {
      const int idx = w * 64 + lane + jj * 512;
      const int rV = idx >> 3, uV = idx & 7;
      __builtin_amdgcn_global_load_lds(
          AS1(Vh + (size_t)rV * 2048 + s0 + ((uV ^ (rV & 7)) << 3)),
          AS3(&Vs[buf][(w * 64 + jj * 512) * 8]), 16, 0, 0);
    }
  };

  // Q load + fused RoPE first (compiler's Q-wait then can't drain staging)
  const int qrow = q0 + l31;
  const float pp = (float)pos[b * 2048 + qrow];
  bf16x8 qf[8];
  {
#pragma unroll
    for (int kd = 0; kd < 4; ++kd) {
      bf16x8 rlo = *(const bf16x8*)(Qh + (size_t)qrow * 4096 + kd * 16 + hi * 8);
      bf16x8 rhi = *(const bf16x8*)(Qh + (size_t)qrow * 4096 + (kd + 4) * 16 + hi * 8);
      bf16x8 olo, ohi;
#pragma unroll
      for (int e = 0; e < 8; ++e) {
        const int j = kd * 16 + hi * 8 + e;
        const float fr = pp * exp2f((float)j * -0.2076205059304601f);
        float sn, cs;
        __sincosf(fr, &sn, &cs);
        const float x0 = __uint_as_float(((unsigned)(unsigned short)rlo[e]) << 16);
        const float x1 = __uint_as_float(((unsigned)(unsigned short)rhi[e]) << 16);
        __hip_bfloat16 h0 = __float2bfloat16((x0 * cs - x1 * sn) * qs);
        __hip_bfloat16 h1 = __float2bfloat16((x1 * cs + x0 * sn) * qs);
        olo[e] = *(short*)&h0;
        ohi[e] = *(short*)&h1;
      }
      qf[kd] = olo;
      qf[kd + 4] = ohi;
    }
  }

  bf16x8 ones;
#pragma unroll
  for (int e = 0; e < 8; ++e) ones[e] = (short)0x3F80;

  // prologue staging: V(0), K(0), K(1)  (6 loads in flight)
  stageV(0, 0);
  stageK(0, 0);
  stageK(1, 64);

  f32x16 o[4] = {};
  f32x16 ol = {};

  int kcur = 0;  // Ks index holding tile j
  for (int j = 0; j < 32; ++j) {
    const int vcur = j & 1;
    const int knx2 = (kcur >= 1) ? kcur - 1 : 2;   // (j+2)%3

    // issue next stages: V first, then K (vmcnt count math depends on this order)
    if (j + 1 < 32) stageV(vcur ^ 1, (j + 1) * 64);
    if (j + 2 < 32) stageK(knx2, (j + 2) * 64);
    // counted wait: guarantee K(j),V(j) landed; keep {K(j+1),V(j+1),K(j+2)} in flight
    if (j < 30)       asm volatile("s_waitcnt vmcnt(6)" ::: "memory");
    else if (j == 30) asm volatile("s_waitcnt vmcnt(4)" ::: "memory");
    else              asm volatile("s_waitcnt vmcnt(0)" ::: "memory");
    __builtin_amdgcn_s_barrier();   // RAW: all waves' shares of tile j landed

    // ---- QK(j) from Ks[kcur]
    f32x16 p[2] = {};
    __builtin_amdgcn_s_setprio(1);
#pragma unroll
    for (int n = 0; n < 2; ++n)
#pragma unroll
      for (int kd = 0; kd < 8; ++kd) {
        const int row = n * 32 + l31;
        bf16x8 kf = *(const bf16x8*)(&Ks[kcur][row * 128 + (((2 * kd + hi) ^ (row & 7)) << 3)]);
        p[n] = __builtin_amdgcn_mfma_f32_32x32x16_bf16(kf, qf[kd], p[n], 0, 0, 0);
      }
    __builtin_amdgcn_s_setprio(0);

    // max-free softmax: P = exp2(S)
#pragma unroll
    for (int n = 0; n < 2; ++n)
#pragma unroll
      for (int e = 0; e < 16; ++e) p[n][e] = exp2f(p[n][e]);

    // pack P -> bf16 B-fragments
    bf16x8 paf[4];
#pragma unroll
    for (int n = 0; n < 2; ++n)
#pragma unroll
      for (int ks = 0; ks < 2; ++ks) {
        const int bse = ks * 8;
        unsigned a1 = cvtpk_bf16(p[n][bse + 0], p[n][bse + 1]);
        unsigned b1 = cvtpk_bf16(p[n][bse + 4], p[n][bse + 5]);
        unsigned a2 = cvtpk_bf16(p[n][bse + 2], p[n][bse + 3]);
        unsigned b2 = cvtpk_bf16(p[n][bse + 6], p[n][bse + 7]);
        uint2x s1 = plswap(a1, b1);
        uint2x s2 = plswap(a2, b2);
        union { unsigned u[4]; bf16x8 v; } pw = {{s1[0], s2[0], s1[1], s2[1]}};
        paf[n * 2 + ks] = pw.v;
      }

    // O^T += V^T P^T ; ol += 1^T P
    __builtin_amdgcn_s_setprio(1);
#pragma unroll
    for (int slot = 0; slot < 4; ++slot) {
      ol = __builtin_amdgcn_mfma_f32_32x32x16_bf16(ones, paf[slot], ol, 0, 0, 0);
#pragma unroll
      for (int dc = 0; dc < 4; ++dc) {
        const int row = dc * 32 + l31;
        bf16x8 vf = *(const bf16x8*)(&Vs[vcur][row * 64 + (((2 * slot + hi) ^ (row & 7)) << 3)]);
        o[dc] = __builtin_amdgcn_mfma_f32_32x32x16_bf16(vf, paf[slot], o[dc], 0, 0, 0);
      }
    }
    __builtin_amdgcn_s_setprio(0);
    __builtin_amdgcn_s_barrier();   // WAR: done reading bufs before next iter's stages
    kcur = (kcur == 2) ? 0 : kcur + 1;
  }

  const float inv = 1.0f / ol[0];
  const size_t rowbase = ((size_t)(b * 2048 + q0 + l31)) * 4096 + h * 128;
#pragma unroll
  for (int dc = 0; dc < 4; ++dc)
#pragma unroll
    for (int g = 0; g < 4; ++g) {
      union { unsigned short us[4]; ushort4 u4; } pk;
#pragma unroll
      for (int e = 0; e < 4; ++e) {
        __hip_bfloat16 hv = __float2bfloat16(o[dc][g * 4 + e] * inv);
        pk.us[e] = *(unsigned short*)&hv;
      }
      *(ushort4*)(ctx + rowbase + dc * 32 + g * 8 + hi * 4) = pk.u4;
    }
}

// ---------------- launcher ----------------

extern "C" void kernel_launch(void* const* d_in, const int* in_sizes, int n_in,
                              void* d_out, int out_size, void* d_ws, size_t ws_size,
                              hipStream_t stream) {
  const float* q_in = (const float*)d_in[0];
  const float* k_in = (const float*)d_in[1];
  const float* v_in = (const float*)d_in[2];
  const int* pos    = (const int*)d_in[3];
  const float* Wq   = (const float*)d_in[4];
  const float* Wk   = (const float*)d_in[5];
  const float* Wv   = (const float*)d_in[6];
  const float* Wo   = (const float*)d_in[7];

  char* ws = (char*)d_ws;
  __hip_bfloat16* xbuf = (__hip_bfloat16*)(ws);              // qconv -> kconv -> ctx
  __hip_bfloat16* WqT  = (__hip_bfloat16*)(ws + 33554432);   // WqT -> vconv
  __hip_bfloat16* WkT  = (__hip_bfloat16*)(ws + 67108864);
  __hip_bfloat16* WvT  = (__hip_bfloat16*)(ws + 75497472);
  __hip_bfloat16* WoT  = (__hip_bfloat16*)(ws + 83886080);
  __hip_bfloat16* Qp   = (__hip_bfloat16*)(ws + 117440512);
  __hip_bfloat16* Kp   = (__hip_bfloat16*)(ws + 150994944);
  __hip_bfloat16* VTb  = (__hip_bfloat16*)(ws + 167772160);
  __hip_bfloat16* vconv = WqT;  // WqT dead after gemm256-Q

  // 1) fused prep: all weight transposes + Q conversion (one launch)
  prep<<<dim3(4096, 1, 5), 256, 0, stream>>>(Wq, Wo, Wk, Wv, q_in,
                                             WqT, WoT, WkT, WvT, xbuf);
  // 2) Q projection (Q unroped; RoPE+scale fused into attn Q-load)
  gemm256<0><<<256, 512, 0, stream>>>(xbuf, WqT, Qp, 4096, 4096, 4096);
  // 3) K+V conversions
  xconv_kv<<<dim3(16384, 2), 256, 0, stream>>>(k_in, v_in, xbuf, vconv);
  // 4) 8-phase K+V projection; RoPE-K fused in epilogue; V writes VT directly
  gemm_kv8<<<dim3(128, 1, 2), 512, 0, stream>>>(xbuf, vconv, WkT, WvT, pos, Kp, VTb);
  // 5) attention -> ctx
  attn<<<dim3(8, 32, 2), 512, 0, stream>>>(Qp, Kp, VTb, pos, xbuf,
                                           0.08838834764831845f * 1.4426950408889634f);
  // 6) output projection, f32 epilogue straight to d_out
  gemm256<1><<<256, 512, 0, stream>>>(xbuf, WoT, d_out, 4096, 4096, 4096);
}

// Round 16
// 604.487 us; speedup vs baseline: 1.0327x; 1.0327x over previous
//
#include <hip/hip_runtime.h>
#include <hip/hip_bf16.h>

typedef __attribute__((ext_vector_type(8))) short bf16x8;
typedef __attribute__((ext_vector_type(4))) float f32x4;
typedef __attribute__((ext_vector_type(16))) float f32x16;
typedef __attribute__((ext_vector_type(2))) unsigned uint2x;

#define AS1(p) ((const __attribute__((address_space(1))) void*)(p))
#define AS3(p) ((__attribute__((address_space(3))) void*)(p))

__device__ inline unsigned cvtpk_bf16(float lo, float hi) {
  unsigned r;
  asm("v_cvt_pk_bf16_f32 %0, %1, %2" : "=v"(r) : "v"(lo), "v"(hi));
  return r;
}

__device__ inline uint2x plswap(unsigned a, unsigned b) {
  return __builtin_amdgcn_permlane32_swap(a, b, false, false);
}

// ---------------- fused prep: 4 weight transposes + Q conversion (one launch) -------
__global__ __launch_bounds__(256) void prep(const float* __restrict__ Wq,
                                            const float* __restrict__ Wo,
                                            const float* __restrict__ Wk,
                                            const float* __restrict__ Wv,
                                            const float* __restrict__ q_in,
                                            __hip_bfloat16* __restrict__ WqT,
                                            __hip_bfloat16* __restrict__ WoT,
                                            __hip_bfloat16* __restrict__ WkT,
                                            __hip_bfloat16* __restrict__ WvT,
                                            __hip_bfloat16* __restrict__ qc) {
  const int z = blockIdx.z;
  if (z == 4) {
    const size_t b0 = (size_t)blockIdx.x * 4096;
#pragma unroll
    for (int c = 0; c < 4; ++c) {
      const size_t i = b0 + c * 1024 + threadIdx.x * 4;
      float4 v = *(const float4*)(q_in + i);
      union { __hip_bfloat16 h[4]; ushort4 u; } o;
      o.h[0] = __float2bfloat16(v.x);
      o.h[1] = __float2bfloat16(v.y);
      o.h[2] = __float2bfloat16(v.z);
      o.h[3] = __float2bfloat16(v.w);
      *(ushort4*)(qc + i) = o.u;
    }
    return;
  }
  const int N = (z < 2) ? 4096 : 1024;
  const int n0 = (blockIdx.x & 63) << 6;
  if (n0 >= N) return;
  const int k0 = (blockIdx.x >> 6) << 6;
  const float* W = (z == 0) ? Wq : (z == 1) ? Wo : (z == 2) ? Wk : Wv;
  __hip_bfloat16* WT = (z == 0) ? WqT : (z == 1) ? WoT : (z == 2) ? WkT : WvT;
  __shared__ float t[64][68];
  const int tx = threadIdx.x & 15, ty = threadIdx.x >> 4;
#pragma unroll
  for (int j = 0; j < 4; ++j) {
    const int k = ty + j * 16;
    float4 v = *(const float4*)(W + (size_t)(k0 + k) * N + n0 + tx * 4);
    t[tx * 4 + 0][k] = v.x;
    t[tx * 4 + 1][k] = v.y;
    t[tx * 4 + 2][k] = v.z;
    t[tx * 4 + 3][k] = v.w;
  }
  __syncthreads();
#pragma unroll
  for (int j = 0; j < 4; ++j) {
    const int n = ty + j * 16;
    float4 v = *(const float4*)(&t[n][tx * 4]);
    union { __hip_bfloat16 h[4]; ushort4 u; } o;
    o.h[0] = __float2bfloat16(v.x);
    o.h[1] = __float2bfloat16(v.y);
    o.h[2] = __float2bfloat16(v.z);
    o.h[3] = __float2bfloat16(v.w);
    *(ushort4*)(WT + (size_t)(n0 + n) * 4096 + k0 + tx * 4) = o.u;
  }
}

// K+V conversions (after gemm256-Q frees xbuf/WqT)
__global__ __launch_bounds__(256) void xconv_kv(const float* __restrict__ k_in,
                                                const float* __restrict__ v_in,
                                                __hip_bfloat16* __restrict__ kc,
                                                __hip_bfloat16* __restrict__ vc) {
  const float* in = blockIdx.y ? v_in : k_in;
  __hip_bfloat16* out = blockIdx.y ? vc : kc;
  size_t i = ((size_t)blockIdx.x * 256 + threadIdx.x) * 4;
  float4 v = *(const float4*)(in + i);
  union { __hip_bfloat16 h[4]; ushort4 u; } o;
  o.h[0] = __float2bfloat16(v.x);
  o.h[1] = __float2bfloat16(v.y);
  o.h[2] = __float2bfloat16(v.z);
  o.h[3] = __float2bfloat16(v.w);
  *(ushort4*)(out + i) = o.u;
}

// ---------------- shared 8-phase GEMM machinery (T2+T3+T4+T5) ----------------

__device__ inline int tile_off(int row, int k) {
  return (((row >> 4) << 1) + (k >> 5)) * 512 + (row & 15) * 32 +
         ((k & 31) ^ ((row & 8) << 1));
}

__device__ inline void stageA(const __hip_bfloat16* __restrict__ src, int ld, int row0,
                              int kt, int h, __hip_bfloat16* ldsT, int w, int lane) {
#pragma unroll
  for (int li = 0; li < 2; ++li) {
    const int t = li * 8 + w;
    const int grp = ((t >> 3) << 1) + h;
    const int srl = (t & 7) >> 1, sk = t & 1;
    const int rowbase = grp * 64 + srl * 16;
    __hip_bfloat16* dst = ldsT + ((((rowbase >> 4) << 1) + sk) << 9);
    const int r = lane >> 2;
    const int ku = (lane & 3) ^ ((r & 8) >> 2);
    __builtin_amdgcn_global_load_lds(
        AS1(src + (size_t)(row0 + rowbase + r) * ld + kt + (sk << 5) + (ku << 3)),
        AS3(dst), 16, 0, 0);
  }
}

__device__ inline void stageB(const __hip_bfloat16* __restrict__ src, int ld, int col0,
                              int kt, int h, __hip_bfloat16* ldsT, int w, int lane) {
#pragma unroll
  for (int li = 0; li < 2; ++li) {
    const int t = li * 8 + w;
    const int q = t >> 2;
    const int srl = (t >> 1) & 1, sk = t & 1;
    const int colbase = q * 64 + h * 32 + srl * 16;
    __hip_bfloat16* dst = ldsT + ((((colbase >> 4) << 1) + sk) << 9);
    const int r = lane >> 2;
    const int ku = (lane & 3) ^ ((r & 8) >> 2);
    __builtin_amdgcn_global_load_lds(
        AS1(src + (size_t)(col0 + colbase + r) * ld + kt + (sk << 5) + (ku << 3)),
        AS3(dst), 16, 0, 0);
  }
}

template <int OUT_F32>
__global__ __launch_bounds__(512, 1) void gemm256(const __hip_bfloat16* __restrict__ A,
                                                  const __hip_bfloat16* __restrict__ BT,
                                                  void* __restrict__ Cout,
                                                  int M, int N, int K) {
  __shared__ __align__(16) __hip_bfloat16 lds[2][2][16384];
  const int tid = threadIdx.x;
  const int lane = tid & 63, w = tid >> 6;
  const int l15 = lane & 15, lg = lane >> 4;
  const int wm = w >> 2, wn = w & 3;
  const int nbx = N >> 8;
  const int nwg = (M >> 8) * nbx;
  const int bid = blockIdx.x;
  const int swz = (bid & 7) * (nwg >> 3) + (bid >> 3);
  const int m0 = (swz / nbx) << 8, n0 = (swz % nbx) << 8;

  f32x4 acc[8][4] = {};
  const int NT = K >> 6;

  stageA(A, K, m0, 0, 0, &lds[0][0][0], w, lane);
  stageB(BT, K, n0, 0, 0, &lds[0][1][0], w, lane);
  stageA(A, K, m0, 0, 1, &lds[0][0][0], w, lane);
  stageB(BT, K, n0, 0, 1, &lds[0][1][0], w, lane);
  stageA(A, K, m0, 64, 0, &lds[1][0][0], w, lane);
  stageB(BT, K, n0, 64, 0, &lds[1][1][0], w, lane);
  asm volatile("s_waitcnt vmcnt(4)" ::: "memory");
  __builtin_amdgcn_s_barrier();

  for (int j = 0; j < NT; ++j) {
    const int buf = j & 1;
    const __hip_bfloat16* Ab = &lds[buf][0][0];
    const __hip_bfloat16* Bb = &lds[buf][1][0];
    __hip_bfloat16* An = &lds[buf ^ 1][0][0];
    __hip_bfloat16* Bn = &lds[buf ^ 1][1][0];
    __hip_bfloat16* Ac = &lds[buf][0][0];
    __hip_bfloat16* Bc = &lds[buf][1][0];
    const int kt1 = (j + 1) << 6, kt2 = (j + 2) << 6;
    const bool s1 = (j + 1) < NT, s2 = (j + 2) < NT;

    auto phase = [&](int rq, int cq, int sid) {
      bf16x8 af[2][4], bfr[2][2];
#pragma unroll
      for (int kk = 0; kk < 2; ++kk) {
#pragma unroll
        for (int rf = 0; rf < 4; ++rf)
          af[kk][rf] = *(const bf16x8*)(Ab +
              tile_off(wm * 128 + (rq * 4 + rf) * 16 + l15, kk * 32 + lg * 8));
#pragma unroll
        for (int cf = 0; cf < 2; ++cf)
          bfr[kk][cf] = *(const bf16x8*)(Bb +
              tile_off(wn * 64 + (cq * 2 + cf) * 16 + l15, kk * 32 + lg * 8));
      }
      if (sid == 0)      { if (s1) stageA(A, K, m0, kt1, 1, An, w, lane); }
      else if (sid == 1) { if (s1) stageB(BT, K, n0, kt1, 1, Bn, w, lane); }
      else if (sid == 2) { if (s2) stageA(A, K, m0, kt2, 0, Ac, w, lane); }
      else {
        if (s2) stageB(BT, K, n0, kt2, 0, Bc, w, lane);
        if (s2) asm volatile("s_waitcnt vmcnt(4)" ::: "memory");
        else    asm volatile("s_waitcnt vmcnt(0)" ::: "memory");
      }
      __builtin_amdgcn_s_barrier();
      asm volatile("s_waitcnt lgkmcnt(0)" ::: "memory");
      __builtin_amdgcn_sched_barrier(0);
      __builtin_amdgcn_s_setprio(1);
#pragma unroll
      for (int kk = 0; kk < 2; ++kk)
#pragma unroll
        for (int rf = 0; rf < 4; ++rf)
#pragma unroll
          for (int cf = 0; cf < 2; ++cf)
            acc[rq * 4 + rf][cq * 2 + cf] = __builtin_amdgcn_mfma_f32_16x16x32_bf16(
                af[kk][rf], bfr[kk][cf], acc[rq * 4 + rf][cq * 2 + cf], 0, 0, 0);
      __builtin_amdgcn_s_setprio(0);
      __builtin_amdgcn_s_barrier();
    };
    phase(0, 0, 0);
    phase(0, 1, 1);
    phase(1, 0, 2);
    phase(1, 1, 3);
  }

#pragma unroll
  for (int rf = 0; rf < 8; ++rf)
#pragma unroll
    for (int cf = 0; cf < 4; ++cf)
#pragma unroll
      for (int i = 0; i < 4; ++i) {
        const size_t row = (size_t)(m0 + wm * 128 + rf * 16 + lg * 4 + i);
        const size_t col = (size_t)(n0 + wn * 64 + cf * 16 + l15);
        if (OUT_F32)
          ((float*)Cout)[row * N + col] = acc[rf][cf][i];
        else
          ((__hip_bfloat16*)Cout)[row * N + col] = __float2bfloat16(acc[rf][cf][i]);
      }
}

// ---------------- 8-phase K/V projection + fused RoPE-K epilogue --------------------
__global__ __launch_bounds__(512, 1) void gemm_kv8(const __hip_bfloat16* __restrict__ Ak,
                                                   const __hip_bfloat16* __restrict__ Av,
                                                   const __hip_bfloat16* __restrict__ BkT,
                                                   const __hip_bfloat16* __restrict__ BvT,
                                                   const int* __restrict__ pos,
                                                   __hip_bfloat16* __restrict__ Kp,
                                                   __hip_bfloat16* __restrict__ VT) {
  __shared__ __align__(16) __hip_bfloat16 lds[2][24576];
  const int zz = blockIdx.z;
  const __hip_bfloat16* A  = zz ? Av : Ak;
  const __hip_bfloat16* BT = zz ? BvT : BkT;
  const int K = 4096;
  const int tid = threadIdx.x;
  const int lane = tid & 63, w = tid >> 6;
  const int l15 = lane & 15, lg = lane >> 4;
  const int wm = w >> 2, wn = w & 3;
  const int bid = blockIdx.x;
  const int swz = (bid & 7) * 16 + (bid >> 3);
  const int m0 = (swz >> 2) << 7;
  const int n0 = (swz & 3) << 8;

  auto stgA = [&](int kt, int h, __hip_bfloat16* ldsA) {
    const int r16 = 2 * h + ((w >> 2) << 2) + ((w >> 1) & 1);
    const int sk = w & 1;
    __hip_bfloat16* dst = ldsA + (((r16 << 1) + sk) << 9);
    const int r = lane >> 2;
    const int ku = (lane & 3) ^ ((r & 8) >> 2);
    __builtin_amdgcn_global_load_lds(
        AS1(A + (size_t)(m0 + r16 * 16 + r) * K + kt + (sk << 5) + (ku << 3)),
        AS3(dst), 16, 0, 0);
  };
  auto stgB = [&](int kt, int h, __hip_bfloat16* ldsB) {
#pragma unroll
    for (int li = 0; li < 2; ++li) {
      const int idx = li * 8 + w;
      const int r16 = ((idx >> 2) << 2) + 2 * h + ((idx >> 1) & 1);
      const int sk = idx & 1;
      __hip_bfloat16* dst = ldsB + (((r16 << 1) + sk) << 9);
      const int r = lane >> 2;
      const int ku = (lane & 3) ^ ((r & 8) >> 2);
      __builtin_amdgcn_global_load_lds(
          AS1(BT + (size_t)(n0 + r16 * 16 + r) * K + kt + (sk << 5) + (ku << 3)),
          AS3(dst), 16, 0, 0);
    }
  };

  f32x4 acc[4][4] = {};
  const int NT = K >> 6;

  stgA(0, 0, &lds[0][0]);
  stgB(0, 0, &lds[0][8192]);
  stgA(0, 1, &lds[0][0]);
  stgB(0, 1, &lds[0][8192]);
  stgA(64, 0, &lds[1][0]);
  stgB(64, 0, &lds[1][8192]);
  asm volatile("s_waitcnt vmcnt(3)" ::: "memory");
  __builtin_amdgcn_s_barrier();

  for (int j = 0; j < NT; ++j) {
    const int buf = j & 1;
    const __hip_bfloat16* Ab = &lds[buf][0];
    const __hip_bfloat16* Bb = &lds[buf][8192];
    __hip_bfloat16* An = &lds[buf ^ 1][0];
    __hip_bfloat16* Bn = &lds[buf ^ 1][8192];
    __hip_bfloat16* Ac = &lds[buf][0];
    __hip_bfloat16* Bc = &lds[buf][8192];
    const int kt1 = (j + 1) << 6, kt2 = (j + 2) << 6;
    const bool s1 = (j + 1) < NT, s2 = (j + 2) < NT;

    auto phase = [&](int rq, int cq, int sid) {
      bf16x8 af[2][2], bfr[2][2];
#pragma unroll
      for (int kk = 0; kk < 2; ++kk) {
#pragma unroll
        for (int rf = 0; rf < 2; ++rf)
          af[kk][rf] = *(const bf16x8*)(Ab +
              tile_off(wm * 64 + (rq * 2 + rf) * 16 + l15, kk * 32 + lg * 8));
#pragma unroll
        for (int cf = 0; cf < 2; ++cf)
          bfr[kk][cf] = *(const bf16x8*)(Bb +
              tile_off(wn * 64 + (cq * 2 + cf) * 16 + l15, kk * 32 + lg * 8));
      }
      if (sid == 0)      { if (s1) stgA(kt1, 1, An); }
      else if (sid == 1) { if (s1) stgB(kt1, 1, Bn); }
      else if (sid == 2) { if (s2) stgA(kt2, 0, Ac); }
      else {
        if (s2) stgB(kt2, 0, Bc);
        if (s2) asm volatile("s_waitcnt vmcnt(3)" ::: "memory");
        else    asm volatile("s_waitcnt vmcnt(0)" ::: "memory");
      }
      __builtin_amdgcn_s_barrier();
      asm volatile("s_waitcnt lgkmcnt(0)" ::: "memory");
      __builtin_amdgcn_sched_barrier(0);
      __builtin_amdgcn_s_setprio(1);
#pragma unroll
      for (int kk = 0; kk < 2; ++kk)
#pragma unroll
        for (int rf = 0; rf < 2; ++rf)
#pragma unroll
          for (int cf = 0; cf < 2; ++cf)
            acc[rq * 2 + rf][cq * 2 + cf] = __builtin_amdgcn_mfma_f32_16x16x32_bf16(
                af[kk][rf], bfr[kk][cf], acc[rq * 2 + rf][cq * 2 + cf], 0, 0, 0);
      __builtin_amdgcn_s_setprio(0);
      __builtin_amdgcn_s_barrier();
    };
    phase(0, 0, 0);
    phase(0, 1, 1);
    phase(1, 0, 2);
    phase(1, 1, 3);
  }

  if (zz == 0) {
    __syncthreads();
    __hip_bfloat16* T = &lds[0][0];         // [128][264]
    const int TS = 264;
#pragma unroll
    for (int rf = 0; rf < 4; ++rf)
#pragma unroll
      for (int cf = 0; cf < 4; ++cf)
#pragma unroll
        for (int i = 0; i < 4; ++i)
          T[(wm * 64 + rf * 16 + lg * 4 + i) * TS + wn * 64 + cf * 16 + l15] =
              __float2bfloat16(acc[rf][cf][i]);
    __syncthreads();
    const int row = tid >> 2, quad = tid & 3;
    const int gr = m0 + row;
    const float p = (float)pos[gr];
#pragma unroll
    for (int qb = 0; qb < 4; ++qb) {
      const int bi = quad + qb * 4;
      const int hl = bi >> 3, jb = (bi & 7) * 8;
      bf16x8 lo  = *(const bf16x8*)&T[row * TS + hl * 128 + jb];
      bf16x8 hi8 = *(const bf16x8*)&T[row * TS + hl * 128 + jb + 64];
      union { __hip_bfloat16 h[8]; bf16x8 v; } o0, o1;
#pragma unroll
      for (int e = 0; e < 8; ++e) {
        const int j = jb + e;
        const float fr = p * exp2f((float)j * -0.2076205059304601f);
        float sn, cs;
        __sincosf(fr, &sn, &cs);
        const float x0 = __uint_as_float(((unsigned)(unsigned short)lo[e]) << 16);
        const float x1 = __uint_as_float(((unsigned)(unsigned short)hi8[e]) << 16);
        o0.h[e] = __float2bfloat16(x0 * cs - x1 * sn);
        o1.h[e] = __float2bfloat16(x1 * cs + x0 * sn);
      }
      *(bf16x8*)(Kp + (size_t)gr * 1024 + n0 + hl * 128 + jb)      = o0.v;
      *(bf16x8*)(Kp + (size_t)gr * 1024 + n0 + hl * 128 + jb + 64) = o1.v;
    }
  } else {
    const int b = m0 >> 11, s0g = m0 & 2047;
#pragma unroll
    for (int rf = 0; rf < 4; ++rf)
#pragma unroll
      for (int cf = 0; cf < 4; ++cf) {
        const int d = n0 + wn * 64 + cf * 16 + l15;
        const int g = d >> 7, dl = d & 127;
        const int srow = s0g + wm * 64 + rf * 16 + lg * 4;
        union { __hip_bfloat16 h[4]; unsigned long long u; } pkv;
#pragma unroll
        for (int i = 0; i < 4; ++i) pkv.h[i] = __float2bfloat16(acc[rf][cf][i]);
        *(unsigned long long*)(VT + ((size_t)(b * 8 + g) * 128 + dl) * 2048 + srow) = pkv.u;
      }
  }
}

// ---------------- flash attention (8-warp 32x32; round-14 structure + K &15 swizzle) -
// Max-free softmax + MFMA lsum. K tile rows have 16 x 16B units: XOR with row&15
// (bijective) spreads 32 rows over 16 bank-groups -> 2-way (free) instead of 4-way.
__global__ __launch_bounds__(512) void attn(const __hip_bfloat16* __restrict__ Q,
                                            const __hip_bfloat16* __restrict__ Kp,
                                            const __hip_bfloat16* __restrict__ VT,
                                            const int* __restrict__ pos,
                                            __hip_bfloat16* __restrict__ ctx,
                                            float qs) {
  const int tid = threadIdx.x;
  const int lane = tid & 63, w = tid >> 6;
  const int l31 = lane & 31, hi = lane >> 5;
  const int qt = blockIdx.x, h = blockIdx.y, b = blockIdx.z;
  const int kvh = h >> 2;
  const int q0 = qt * 256 + w * 32;

  const __hip_bfloat16* Qh = Q + (size_t)(b * 2048) * 4096 + h * 128;
  const __hip_bfloat16* Kh = Kp + (size_t)(b * 2048) * 1024 + kvh * 128;
  const __hip_bfloat16* Vh = VT + (size_t)(b * 8 + kvh) * 128 * 2048;

  __shared__ __hip_bfloat16 Ks[2][64 * 128];
  __shared__ __hip_bfloat16 Vs[2][128 * 64];

  auto stage = [&](int buf, int s0) {
#pragma unroll
    for (int j = 0; j < 2; ++j) {
      const int idx = w * 64 + lane + j * 512;
      const int rK = idx >> 4, uK = idx & 15;
      __builtin_amdgcn_global_load_lds(
          AS1(Kh + (size_t)(s0 + rK) * 1024 + ((uK ^ (rK & 15)) << 3)),
          AS3(&Ks[buf][(w * 64 + j * 512) * 8]), 16, 0, 0);
      const int rV = idx >> 3, uV = idx & 7;
      __builtin_amdgcn_global_load_lds(
          AS1(Vh + (size_t)rV * 2048 + s0 + ((uV ^ (rV & 7)) << 3)),
          AS3(&Vs[buf][(w * 64 + j * 512) * 8]), 16, 0, 0);
    }
  };

  stage(0, 0);

  const int qrow = q0 + l31;
  const float pp = (float)pos[b * 2048 + qrow];
  bf16x8 qf[8];
  {
#pragma unroll
    for (int kd = 0; kd < 4; ++kd) {
      bf16x8 rlo = *(const bf16x8*)(Qh + (size_t)qrow * 4096 + kd * 16 + hi * 8);
      bf16x8 rhi = *(const bf16x8*)(Qh + (size_t)qrow * 4096 + (kd + 4) * 16 + hi * 8);
      bf16x8 olo, ohi;
#pragma unroll
      for (int e = 0; e < 8; ++e) {
        const int j = kd * 16 + hi * 8 + e;
        const float fr = pp * exp2f((float)j * -0.2076205059304601f);
        float sn, cs;
        __sincosf(fr, &sn, &cs);
        const float x0 = __uint_as_float(((unsigned)(unsigned short)rlo[e]) << 16);
        const float x1 = __uint_as_float(((unsigned)(unsigned short)rhi[e]) << 16);
        __hip_bfloat16 h0 = __float2bfloat16((x0 * cs - x1 * sn) * qs);
        __hip_bfloat16 h1 = __float2bfloat16((x1 * cs + x0 * sn) * qs);
        olo[e] = *(short*)&h0;
        ohi[e] = *(short*)&h1;
      }
      qf[kd] = olo;
      qf[kd + 4] = ohi;
    }
  }

  bf16x8 ones;
#pragma unroll
  for (int e = 0; e < 8; ++e) ones[e] = (short)0x3F80;

  f32x16 o[4] = {};
  f32x16 ol = {};
  __syncthreads();

  auto tile = [&](int tt, int cur, bool pf) {
    if (pf) stage(cur ^ 1, (tt + 1) * 64);

    f32x16 p[2] = {};
    __builtin_amdgcn_s_setprio(1);
#pragma unroll
    for (int n = 0; n < 2; ++n)
#pragma unroll
      for (int kd = 0; kd < 8; ++kd) {
        const int row = n * 32 + l31;
        bf16x8 kf = *(const bf16x8*)(&Ks[cur][row * 128 + (((2 * kd + hi) ^ (row & 15)) << 3)]);
        p[n] = __builtin_amdgcn_mfma_f32_32x32x16_bf16(kf, qf[kd], p[n], 0, 0, 0);
      }
    __builtin_amdgcn_s_setprio(0);

#pragma unroll
    for (int n = 0; n < 2; ++n)
#pragma unroll
      for (int e = 0; e < 16; ++e) p[n][e] = exp2f(p[n][e]);

    bf16x8 paf[4];
#pragma unroll
    for (int n = 0; n < 2; ++n)
#pragma unroll
      for (int ks = 0; ks < 2; ++ks) {
        const int bse = ks * 8;
        unsigned a1 = cvtpk_bf16(p[n][bse + 0], p[n][bse + 1]);
        unsigned b1 = cvtpk_bf16(p[n][bse + 4], p[n][bse + 5]);
        unsigned a2 = cvtpk_bf16(p[n][bse + 2], p[n][bse + 3]);
        unsigned b2 = cvtpk_bf16(p[n][bse + 6], p[n][bse + 7]);
        uint2x s1 = plswap(a1, b1);
        uint2x s2 = plswap(a2, b2);
        union { unsigned u[4]; bf16x8 v; } pw = {{s1[0], s2[0], s1[1], s2[1]}};
        paf[n * 2 + ks] = pw.v;
      }

    __builtin_amdgcn_s_setprio(1);
#pragma unroll
    for (int slot = 0; slot < 4; ++slot) {
      ol = __builtin_amdgcn_mfma_f32_32x32x16_bf16(ones, paf[slot], ol, 0, 0, 0);
#pragma unroll
      for (int dc = 0; dc < 4; ++dc) {
        const int row = dc * 32 + l31;
        bf16x8 vf = *(const bf16x8*)(&Vs[cur][row * 64 + (((2 * slot + hi) ^ (row & 7)) << 3)]);
        o[dc] = __builtin_amdgcn_mfma_f32_32x32x16_bf16(vf, paf[slot], o[dc], 0, 0, 0);
      }
    }
    __builtin_amdgcn_s_setprio(0);
    __syncthreads();
  };

  for (int t2 = 0; t2 < 16; ++t2) {
    tile(2 * t2, 0, true);
    tile(2 * t2 + 1, 1, t2 < 15);
  }

  const float inv = 1.0f / ol[0];
  const size_t rowbase = ((size_t)(b * 2048 + q0 + l31)) * 4096 + h * 128;
#pragma unroll
  for (int dc = 0; dc < 4; ++dc)
#pragma unroll
    for (int g = 0; g < 4; ++g) {
      union { unsigned short us[4]; ushort4 u4; } pk;
#pragma unroll
      for (int e = 0; e < 4; ++e) {
        __hip_bfloat16 hv = __float2bfloat16(o[dc][g * 4 + e] * inv);
        pk.us[e] = *(unsigned short*)&hv;
      }
      *(ushort4*)(ctx + rowbase + dc * 32 + g * 8 + hi * 4) = pk.u4;
    }
}

// ---------------- launcher ----------------

extern "C" void kernel_launch(void* const* d_in, const int* in_sizes, int n_in,
                              void* d_out, int out_size, void* d_ws, size_t ws_size,
                              hipStream_t stream) {
  const float* q_in = (const float*)d_in[0];
  const float* k_in = (const float*)d_in[1];
  const float* v_in = (const float*)d_in[2];
  const int* pos    = (const int*)d_in[3];
  const float* Wq   = (const float*)d_in[4];
  const float* Wk   = (const float*)d_in[5];
  const float* Wv   = (const float*)d_in[6];
  const float* Wo   = (const float*)d_in[7];

  char* ws = (char*)d_ws;
  __hip_bfloat16* xbuf = (__hip_bfloat16*)(ws);              // qconv -> kconv -> ctx
  __hip_bfloat16* WqT  = (__hip_bfloat16*)(ws + 33554432);   // WqT -> vconv
  __hip_bfloat16* WkT  = (__hip_bfloat16*)(ws + 67108864);
  __hip_bfloat16* WvT  = (__hip_bfloat16*)(ws + 75497472);
  __hip_bfloat16* WoT  = (__hip_bfloat16*)(ws + 83886080);
  __hip_bfloat16* Qp   = (__hip_bfloat16*)(ws + 117440512);
  __hip_bfloat16* Kp   = (__hip_bfloat16*)(ws + 150994944);
  __hip_bfloat16* VTb  = (__hip_bfloat16*)(ws + 167772160);
  __hip_bfloat16* vconv = WqT;  // WqT dead after gemm256-Q

  // 1) fused prep: all weight transposes + Q conversion (one launch)
  prep<<<dim3(4096, 1, 5), 256, 0, stream>>>(Wq, Wo, Wk, Wv, q_in,
                                             WqT, WoT, WkT, WvT, xbuf);
  // 2) Q projection (Q unroped; RoPE+scale fused into attn Q-load)
  gemm256<0><<<256, 512, 0, stream>>>(xbuf, WqT, Qp, 4096, 4096, 4096);
  // 3) K+V conversions
  xconv_kv<<<dim3(16384, 2), 256, 0, stream>>>(k_in, v_in, xbuf, vconv);
  // 4) 8-phase K+V projection; RoPE-K fused in epilogue; V writes VT directly
  gemm_kv8<<<dim3(128, 1, 2), 512, 0, stream>>>(xbuf, vconv, WkT, WvT, pos, Kp, VTb);
  // 5) attention -> ctx
  attn<<<dim3(8, 32, 2), 512, 0, stream>>>(Qp, Kp, VTb, pos, xbuf,
                                           0.08838834764831845f * 1.4426950408889634f);
  // 6) output projection, f32 epilogue straight to d_out
  gemm256<1><<<256, 512, 0, stream>>>(xbuf, WoT, d_out, 4096, 4096, 4096);
}